// Round 11
// baseline (142.666 us; speedup 1.0000x reference)
//
#include <hip/hip_runtime.h>

#define BLANK 36
#define NEG -1e30f
#define CC 37
#define LOG37 3.6109179126442243f

__device__ __forceinline__ float logaddexp_f(float a, float b) {
    float m = fmaxf(a, b);
    float d = fabsf(a - b);
    return m + __logf(1.0f + __expf(-d));
}

// DPP helpers (VALU pipe): 0x110|n = row_shr:n, 0x142 = row_bcast15,
// 0x143 = row_bcast31. bound_ctrl=true -> OOB lanes read 0.
#define DPP0(src, ctrl) __builtin_amdgcn_update_dpp(0, (src), (ctrl), 0xf, 0xf, true)
#define DPPM(old, src, ctrl) __builtin_amdgcn_update_dpp((old), (src), (ctrl), 0xf, 0xf, false)

// ============ FAST PATH: fused, linear domain, DPP shifts, ROLLED ==========
// R10 post-mortem: five different inner loops all plateau at ~200 cyc/step;
// the shared trait is ~30-40 KB of unrolled hot code > 32 KB I-cache -> the
// kernel streams instructions from L2. This version keeps R10's verified
// math but ROLLS the group loop (#pragma unroll 1, ~1 KB hot body), absorbs
// the c==0 peel via runtime g0 (no duplicated chunk body), and uses 2-wave
// blocks for finer CU load balance.
__global__ __launch_bounds__(128) void ctc_fused_roll_kernel(
    const float* __restrict__ logits,        // [B, T, C]
    const int*   __restrict__ targets,       // [B * L]
    const int*   __restrict__ input_lengths, // [B]
    const int*   __restrict__ target_lengths,// [B]
    float*       __restrict__ per_sample,    // [B]
    int B, int T, int L)
{
    __shared__ float lds[2 * 4736];
    const int lane = threadIdx.x & 63;
    const int wib  = threadIdx.x >> 6;       // 0..1
    const int b    = blockIdx.x * 2 + wib;
    if (b >= B) return;

    float* X0 = lds + wib * 4736;
    float* X1 = X0 + 2368;

    const int S = 2 * L + 1;
    const int tlen_s = __builtin_amdgcn_readfirstlane(target_lengths[b]);
    const int ilen_s = __builtin_amdgcn_readfirstlane(input_lengths[b]);
    const int end_s  = 2 * tlen_s;

    int ext_s = BLANK;                 // < CC always -> LDS gathers in-bounds
    if (lane < S && (lane & 1)) ext_s = targets[b * L + (lane >> 1)];
    const int es2 = __shfl_up(ext_s, 2);
    const bool skip_ok = (lane < S) && (lane >= 2) && (ext_s != BLANK) && (ext_s != es2);
    const float kf = skip_ok ? 1.0f : 0.0f;
    const bool valid = lane < (2 * tlen_s + 1);
    const float validm = valid ? 1.0f : 0.0f;

    // row-boundary lanes for DPP shift patches (verified in R10, absmax 0)
    const bool c16 = ((lane & 31) == 16);
    const bool c17 = ((lane & 31) == 17);
    const bool c32 = (lane == 32);
    const bool c33 = (lane == 33);

    const float4* src = (const float4*)(logits + (size_t)b * T * CC);

    float z = 0.0f, racc = 0.0f, capv = NEG;

    auto STEP = [&](float p, int tt) {       // p includes validm
        const int zi  = __float_as_int(z);
        const int s1  = DPP0(zi, 0x111);
        const int s2  = DPP0(zi, 0x112);
        const int b15 = DPP0(zi, 0x142);
        const int b31 = DPP0(zi, 0x143);
        const int y15 = DPP0(s1, 0x142);
        const int y31 = DPP0(s1, 0x143);
        const float a1 = __int_as_float(c16 ? b15 : (c32 ? b31 : s1));
        const float a2 = __int_as_float(c16 ? y15 : (c17 ? b15 : (c32 ? y31 : (c33 ? b31 : s2))));
        z = fmaf(kf, a2, z + a1) * p;
        if (ilen_s == tt + 1)                // wave-uniform scalar branch
            capv = __logf(fmaxf(z, 1e-35f)) + racc - (float)(tt + 1) * LOG37;
    };

    auto RESCALE = [&]() {                   // DPP max-reduce, LDS-free
        float m = z;
        m = fmaxf(m, __int_as_float(DPPM(__float_as_int(m), __float_as_int(m), 0x111)));
        m = fmaxf(m, __int_as_float(DPPM(__float_as_int(m), __float_as_int(m), 0x112)));
        m = fmaxf(m, __int_as_float(DPPM(__float_as_int(m), __float_as_int(m), 0x114)));
        m = fmaxf(m, __int_as_float(DPPM(__float_as_int(m), __float_as_int(m), 0x118)));
        m = fmaxf(m, __int_as_float(DPPM(__float_as_int(m), __float_as_int(m), 0x142)));
        m = fmaxf(m, __int_as_float(DPPM(__float_as_int(m), __float_as_int(m), 0x143)));
        float gm = __shfl(m, 63);
        gm = fmaxf(gm, 1e-30f);
        z *= (1.0f / gm);
        racc += __logf(gm);
    };

    auto SOFTMAX = [&](float* Xn) {          // in-place row softmax scaled by 37
        float xr[CC];
        const float* row = Xn + lane * CC;
        #pragma unroll
        for (int c2 = 0; c2 < CC; ++c2) xr[c2] = row[c2];
        float m = xr[0];
        #pragma unroll
        for (int c2 = 1; c2 < CC; ++c2) m = fmaxf(m, xr[c2]);
        float ss = 0.0f;
        #pragma unroll
        for (int c2 = 0; c2 < CC; ++c2) { xr[c2] = __expf(xr[c2] - m); ss += xr[c2]; }
        const float inv = 37.0f / ss;
        float* wrow = Xn + lane * CC;
        #pragma unroll
        for (int c2 = 0; c2 < CC; ++c2) wrow[c2] = xr[c2] * inv;
    };

    // ---- prologue: stage + softmax chunk 0 ----
    {
        float4* dst = (float4*)X0;
        #pragma unroll
        for (int k = 0; k < 9; ++k) dst[k * 64 + lane] = src[k * 64 + lane];
        if (lane < 16) dst[576 + lane] = src[576 + lane];   // 592 = 9*64+16
        __builtin_amdgcn_s_waitcnt(0);
        SOFTMAX(X0);
        __builtin_amdgcn_s_waitcnt(0);
    }

    // ---- t=0 init + steps 1..3 (peel; lets every chunk share one body) ----
    {
        const float p00 = X0[ext_s] * validm;
        z = (lane <= 1) ? p00 : 0.0f;
        if (ilen_s == 1) capv = __logf(fmaxf(z, 1e-35f)) - LOG37;
        #pragma unroll
        for (int j = 1; j < 4; ++j) {
            const float pj = X0[j * CC + ext_s] * validm;
            STEP(pj, j);
        }
    }

    const int NC = T >> 6;            // chunks of 64 (T % 64 == 0 on this path)
    for (int c = 0; c < NC; ++c) {
        float* Xb = (c & 1) ? X1 : X0;
        const bool more = (c + 1 < NC);

        // (a) issue global loads for chunk c+1 (named regs; hidden by (b))
        float4 f0 = {}, f1 = {}, f2 = {}, f3 = {}, f4 = {},
               f5 = {}, f6 = {}, f7 = {}, f8 = {}, f9 = {};
        if (more) {
            const float4* s2g = src + (size_t)(c + 1) * 592;
            f0 = s2g[lane];       f1 = s2g[64 + lane];  f2 = s2g[128 + lane];
            f3 = s2g[192 + lane]; f4 = s2g[256 + lane]; f5 = s2g[320 + lane];
            f6 = s2g[384 + lane]; f7 = s2g[448 + lane]; f8 = s2g[512 + lane];
            if (lane < 16) f9 = s2g[576 + lane];
        }

        // (b) rolled group loop; 4-slot lookahead, runtime g0 absorbs peel
        const int tbase = c << 6;
        const int g0 = (c == 0) ? 1 : 0;
        const float* gp = Xb + ext_s;
        int row = g0 << 2;
        float p0 = gp[(row + 0) * CC] * validm;
        float p1 = gp[(row + 1) * CC] * validm;
        float p2 = gp[(row + 2) * CC] * validm;
        float p3 = gp[(row + 3) * CC] * validm;
        #pragma unroll 1
        for (int g = g0; g < 16; ++g) {
            float q0, q1, q2, q3;
            if (g < 15) {
                q0 = gp[(row + 4) * CC] * validm;
                q1 = gp[(row + 5) * CC] * validm;
                q2 = gp[(row + 6) * CC] * validm;
                q3 = gp[(row + 7) * CC] * validm;
            }
            const int tt = tbase + row;
            STEP(p0, tt); STEP(p1, tt + 1); STEP(p2, tt + 2); STEP(p3, tt + 3);
            p0 = q0; p1 = q1; p2 = q2; p3 = q3;
            row += 4;
            if ((g & 3) == 3) RESCALE();     // every 16 steps
        }

        // (c) commit staged chunk c+1, softmax rows in place
        if (more) {
            float* Xn = (c & 1) ? X0 : X1;
            float4* dst = (float4*)Xn;
            dst[lane] = f0;       dst[64 + lane] = f1;  dst[128 + lane] = f2;
            dst[192 + lane] = f3; dst[256 + lane] = f4; dst[320 + lane] = f5;
            dst[384 + lane] = f6; dst[448 + lane] = f7; dst[512 + lane] = f8;
            if (lane < 16) dst[576 + lane] = f9;
            __builtin_amdgcn_s_waitcnt(0);
            SOFTMAX(Xn);
            __builtin_amdgcn_s_waitcnt(0);
        }
    }

    // ---- final_ll once ----
    const float e1 = __shfl(capv, end_s);
    const float e2 = __shfl(capv, end_s - 1);
    const float final_v = logaddexp_f(e1, e2);
    if (lane == 0) per_sample[b] = -final_v / (float)tlen_s;
}

// ============ FALLBACK PATH (proven R2 kernels) ============================
__global__ __launch_bounds__(256) void lse_kernel(
    const float* __restrict__ logits, float* __restrict__ denom, int N)
{
    __shared__ float lds[256 * CC];
    const int lane = threadIdx.x & 63;
    const int wib  = threadIdx.x >> 6;
    const int wave = blockIdx.x * 4 + wib;
    const long long row0 = (long long)wave * 64;
    if (row0 >= N) return;
    const int wbase = wib * 64 * CC;
    const float4* src4 = (const float4*)(logits + row0 * CC);
    const long long n4_remaining = ((long long)N * CC - row0 * CC) / 4;
    float4* lds4 = (float4*)(lds + wbase);
    #pragma unroll
    for (int k = 0; k < 10; ++k) {
        const int idx = k * 64 + lane;
        if (idx < 592 && idx < n4_remaining) lds4[idx] = src4[idx];
    }
    __builtin_amdgcn_s_waitcnt(0);
    const long long row = row0 + lane;
    if (row >= N) return;
    const float* x = lds + wbase + lane * CC;
    float m = x[0];
    #pragma unroll
    for (int c = 1; c < CC; ++c) m = fmaxf(m, x[c]);
    float s = 0.0f;
    #pragma unroll
    for (int c = 0; c < CC; ++c) s += __expf(x[c] - m);
    denom[row] = m + __logf(s);
}

__global__ __launch_bounds__(256) void ctc_alpha2_kernel(
    const float* __restrict__ logits, const float* __restrict__ denom,
    const int* __restrict__ targets, const int* __restrict__ input_lengths,
    const int* __restrict__ target_lengths, float* __restrict__ per_sample,
    int B, int T, int L)
{
    const int wave = (int)((blockIdx.x * blockDim.x + threadIdx.x) >> 6);
    const int lane = threadIdx.x & 63;
    if (wave >= B) return;
    const int b = wave;
    const int S = 2 * L + 1;
    const int tlen = target_lengths[b];
    const int ilen = input_lengths[b];
    const int end_idx = 2 * tlen;
    int ext_s = BLANK;
    if (lane < S && (lane & 1)) ext_s = targets[b * L + (lane >> 1)];
    const int ext_sm2 = __shfl_up(ext_s, 2);
    const bool skip_ok = (lane < S) && (lane >= 2) && (ext_s != BLANK) && (ext_s != ext_sm2);
    const bool valid = lane < (2 * tlen + 1);
    const float* lg = logits + (size_t)b * T * CC;
    const float* dn = denom + (size_t)b * T;
    float x_cur = lg[ext_s];
    float d_cur = dn[0];
    float x_nx = (T > 1) ? lg[CC + ext_s] : 0.0f;
    float d_nx = (T > 1) ? dn[1] : 0.0f;
    float final_v = NEG;
    float alpha = (valid && lane <= 1) ? (x_cur - d_cur) : NEG;
    if (ilen == 1) {
        const float e1 = __shfl(alpha, end_idx);
        const float e2 = __shfl(alpha, end_idx - 1);
        final_v = logaddexp_f(e1, e2);
    }
    for (int tt = 1; tt < T; ++tt) {
        x_cur = x_nx; d_cur = d_nx;
        if (tt + 1 < T) {
            x_nx = lg[(size_t)(tt + 1) * CC + ext_s];
            d_nx = dn[tt + 1];
        }
        const float lpe = x_cur - d_cur;
        float a1 = __shfl_up(alpha, 1);
        if (lane == 0) a1 = NEG;
        float a2 = __shfl_up(alpha, 2);
        if (!skip_ok) a2 = NEG;
        const float m = fmaxf(fmaxf(alpha, a1), a2);
        const float s = __expf(alpha - m) + __expf(a1 - m) + __expf(a2 - m);
        const float na = m + __logf(s) + lpe;
        alpha = valid ? na : NEG;
        if (ilen == tt + 1) {
            const float e1 = __shfl(alpha, end_idx);
            const float e2 = __shfl(alpha, end_idx - 1);
            final_v = logaddexp_f(e1, e2);
        }
    }
    if (lane == 0) per_sample[b] = -final_v / (float)tlen;
}

__global__ __launch_bounds__(256) void ctc_alpha_mono_kernel(
    const float* __restrict__ logits, const int* __restrict__ targets,
    const int* __restrict__ input_lengths, const int* __restrict__ target_lengths,
    float* __restrict__ per_sample, int B, int T, int L)
{
    const int wave = (int)((blockIdx.x * blockDim.x + threadIdx.x) >> 6);
    const int lane = threadIdx.x & 63;
    if (wave >= B) return;
    const int b = wave;
    const int S = 2 * L + 1;
    const int tlen = target_lengths[b];
    const int ilen = input_lengths[b];
    const int end_idx = 2 * tlen;
    int ext_s = BLANK;
    if (lane < S && (lane & 1)) ext_s = targets[b * L + (lane >> 1)];
    const int ext_sm2 = __shfl_up(ext_s, 2);
    const bool skip_ok = (lane < S) && (lane >= 2) && (ext_s != BLANK) && (ext_s != ext_sm2);
    const bool valid = lane < (2 * tlen + 1);
    const float* lg = logits + (size_t)b * T * CC;
    float alpha = NEG, final_v = NEG;
    for (int t = 0; t < T; ++t) {
        float x = (lane < CC) ? lg[t * CC + lane] : -3.0e38f;
        float mx = x;
        #pragma unroll
        for (int o = 32; o > 0; o >>= 1) mx = fmaxf(mx, __shfl_xor(mx, o));
        float e = (lane < CC) ? __expf(x - mx) : 0.0f;
        float se = e;
        #pragma unroll
        for (int o = 32; o > 0; o >>= 1) se += __shfl_xor(se, o);
        const float lp = x - mx - __logf(se);
        const float lpe = __shfl(lp, ext_s);
        float newa;
        if (t == 0) {
            newa = (lane <= 1) ? lpe : NEG;
        } else {
            float a1 = __shfl_up(alpha, 1);
            if (lane == 0) a1 = NEG;
            float a2 = __shfl_up(alpha, 2);
            if (!skip_ok) a2 = NEG;
            newa = logaddexp_f(logaddexp_f(alpha, a1), a2) + lpe;
        }
        if (!valid) newa = NEG;
        alpha = newa;
        if (ilen == t + 1) {
            const float e1 = __shfl(alpha, end_idx);
            const float e2 = __shfl(alpha, end_idx - 1);
            final_v = logaddexp_f(e1, e2);
        }
    }
    if (lane == 0) per_sample[b] = -final_v / (float)tlen;
}

// ---------------- Deterministic mean over B samples ------------------------
__global__ __launch_bounds__(256) void reduce_mean_kernel(
    const float* __restrict__ ps, float* __restrict__ out, int B)
{
    float s = 0.0f;
    for (int i = threadIdx.x; i < B; i += 256) s += ps[i];
    #pragma unroll
    for (int o = 32; o > 0; o >>= 1) s += __shfl_xor(s, o);
    __shared__ float sm[4];
    const int w = threadIdx.x >> 6, l = threadIdx.x & 63;
    if (l == 0) sm[w] = s;
    __syncthreads();
    if (threadIdx.x == 0) {
        out[0] = (sm[0] + sm[1] + sm[2] + sm[3]) / (float)B;
    }
}

extern "C" void kernel_launch(void* const* d_in, const int* in_sizes, int n_in,
                              void* d_out, int out_size, void* d_ws, size_t ws_size,
                              hipStream_t stream) {
    const float* logits         = (const float*)d_in[0];
    const int*   targets        = (const int*)d_in[1];
    const int*   input_lengths  = (const int*)d_in[2];
    const int*   target_lengths = (const int*)d_in[3];

    const int B = in_sizes[2];
    const int L = in_sizes[1] / B;
    const int T = in_sizes[0] / (B * CC);
    const long long N = (long long)B * T;

    float* per_sample = (float*)d_ws;
    float* scratch    = per_sample + B;
    float* out        = (float*)d_out;

    const size_t ws_mid = ((size_t)B + (size_t)N) * sizeof(float);
    const int nblocks_alpha = (B * 64 + 255) / 256;
    const long long nwaves = (N + 63) / 64;

    if ((T % 64 == 0) && T >= 64 && L <= 31 && ws_size >= (size_t)B * sizeof(float)) {
        ctc_fused_roll_kernel<<<(B + 1) / 2, 128, 0, stream>>>(
            logits, targets, input_lengths, target_lengths, per_sample, B, T, L);
    } else if (ws_size >= ws_mid && T >= 2) {
        lse_kernel<<<(int)((nwaves + 3) / 4), 256, 0, stream>>>(logits, scratch, (int)N);
        ctc_alpha2_kernel<<<nblocks_alpha, 256, 0, stream>>>(
            logits, scratch, targets, input_lengths, target_lengths, per_sample, B, T, L);
    } else {
        ctc_alpha_mono_kernel<<<nblocks_alpha, 256, 0, stream>>>(
            logits, targets, input_lengths, target_lengths, per_sample, B, T, L);
    }
    reduce_mean_kernel<<<1, 256, 0, stream>>>(per_sample, out, B);
}

// Round 12
// 137.945 us; speedup vs baseline: 1.0342x; 1.0342x over previous
//
#include <hip/hip_runtime.h>

#define BLANK 36
#define NEG -1e30f
#define CC 37
#define LOG37 3.6109179126442243f

__device__ __forceinline__ float logaddexp_f(float a, float b) {
    float m = fmaxf(a, b);
    float d = fabsf(a - b);
    return m + __logf(1.0f + __expf(-d));
}

// DPP helpers (VALU pipe): 0x110|n = row_shr:n, 0x142 = row_bcast15,
// 0x143 = row_bcast31. bound_ctrl=true -> OOB lanes read 0.
#define DPP0(src, ctrl) __builtin_amdgcn_update_dpp(0, (src), (ctrl), 0xf, 0xf, true)
#define DPPM(old, src, ctrl) __builtin_amdgcn_update_dpp((old), (src), (ctrl), 0xf, 0xf, false)

// ============ FAST PATH: DPP recurrence + 16-step static-window lookahead ==
// R11 post-mortem: every prior variant gave the per-step LDS gather only ~4
// steps (~120 cyc) of cover vs an LDS latency of 120+ (queued: more) ->
// per-step lgkmcnt stall, unhidden at 2 waves/SIMD. This version: pw[16]
// rotating window, ALL indices static after unroll (registers, no scratch),
// 16-step (~480 cyc) cover. Rescale uses v_readlane (no ds_bpermute).
// Linear-domain math identical to R10/R11 (absmax 0 verified).
__global__ __launch_bounds__(128) void ctc_fused_dpp16_kernel(
    const float* __restrict__ logits,        // [B, T, C]
    const int*   __restrict__ targets,       // [B * L]
    const int*   __restrict__ input_lengths, // [B]
    const int*   __restrict__ target_lengths,// [B]
    float*       __restrict__ per_sample,    // [B]
    int B, int T, int L)
{
    __shared__ float lds[2 * 4736];
    const int lane = threadIdx.x & 63;
    const int wib  = threadIdx.x >> 6;       // 0..1
    const int b    = blockIdx.x * 2 + wib;
    if (b >= B) return;

    float* X0 = lds + wib * 4736;
    float* X1 = X0 + 2368;

    const int S = 2 * L + 1;
    const int tlen_s = __builtin_amdgcn_readfirstlane(target_lengths[b]);
    const int ilen_s = __builtin_amdgcn_readfirstlane(input_lengths[b]);
    const int end_s  = 2 * tlen_s;

    int ext_s = BLANK;                 // < CC always -> LDS gathers in-bounds
    if (lane < S && (lane & 1)) ext_s = targets[b * L + (lane >> 1)];
    const int es2 = __shfl_up(ext_s, 2);
    const bool skip_ok = (lane < S) && (lane >= 2) && (ext_s != BLANK) && (ext_s != es2);
    const float kf = skip_ok ? 1.0f : 0.0f;
    const bool valid = lane < (2 * tlen_s + 1);
    const float validm = valid ? 1.0f : 0.0f;

    // row-boundary lanes for DPP shift patches (verified R10/R11, absmax 0)
    const bool c16 = ((lane & 31) == 16);
    const bool c17 = ((lane & 31) == 17);
    const bool c32 = (lane == 32);
    const bool c33 = (lane == 33);

    const float4* src = (const float4*)(logits + (size_t)b * T * CC);

    float z = 0.0f, racc = 0.0f, capv = NEG;

    // NOTE: no per-step valid mask. Invalid lanes (>= S) evolve freely but
    // DPP shifts only move data toward HIGHER lanes, so they never feed valid
    // lanes; rescale's gm including them is exactness-neutral (racc absorbs).
    auto STEP = [&](float p, int tt) {
        const int zi  = __float_as_int(z);
        const int s1  = DPP0(zi, 0x111);
        const int s2  = DPP0(zi, 0x112);
        const int b15 = DPP0(zi, 0x142);
        const int b31 = DPP0(zi, 0x143);
        const int y15 = DPP0(s1, 0x142);
        const int y31 = DPP0(s1, 0x143);
        const float a1 = __int_as_float(c16 ? b15 : (c32 ? b31 : s1));
        const float a2 = __int_as_float(c16 ? y15 : (c17 ? b15 : (c32 ? y31 : (c33 ? b31 : s2))));
        z = fmaf(kf, a2, z + a1) * p;
        if (ilen_s == tt + 1)                // wave-uniform scalar branch
            capv = __logf(fmaxf(z, 1e-35f)) + racc - (float)(tt + 1) * LOG37;
    };

    auto RESCALE = [&]() {                   // DPP reduce + readlane: LDS-free
        float m = z;
        m = fmaxf(m, __int_as_float(DPPM(__float_as_int(m), __float_as_int(m), 0x111)));
        m = fmaxf(m, __int_as_float(DPPM(__float_as_int(m), __float_as_int(m), 0x112)));
        m = fmaxf(m, __int_as_float(DPPM(__float_as_int(m), __float_as_int(m), 0x114)));
        m = fmaxf(m, __int_as_float(DPPM(__float_as_int(m), __float_as_int(m), 0x118)));
        m = fmaxf(m, __int_as_float(DPPM(__float_as_int(m), __float_as_int(m), 0x142)));
        m = fmaxf(m, __int_as_float(DPPM(__float_as_int(m), __float_as_int(m), 0x143)));
        float gm = __int_as_float(__builtin_amdgcn_readlane(__float_as_int(m), 63));
        gm = fmaxf(gm, 1e-30f);
        z *= (1.0f / gm);
        racc += __logf(gm);
    };

    auto SOFTMAX = [&](float* Xn) {          // in-place row softmax scaled by 37
        float xr[CC];
        const float* row = Xn + lane * CC;
        #pragma unroll
        for (int c2 = 0; c2 < CC; ++c2) xr[c2] = row[c2];
        float m = xr[0];
        #pragma unroll
        for (int c2 = 1; c2 < CC; ++c2) m = fmaxf(m, xr[c2]);
        float ss = 0.0f;
        #pragma unroll
        for (int c2 = 0; c2 < CC; ++c2) { xr[c2] = __expf(xr[c2] - m); ss += xr[c2]; }
        const float inv = 37.0f / ss;
        float* wrow = Xn + lane * CC;
        #pragma unroll
        for (int c2 = 0; c2 < CC; ++c2) wrow[c2] = xr[c2] * inv;
    };

    // ---- prologue: stage + softmax chunk 0 ----
    {
        float4* dst = (float4*)X0;
        #pragma unroll
        for (int k = 0; k < 9; ++k) dst[k * 64 + lane] = src[k * 64 + lane];
        if (lane < 16) dst[576 + lane] = src[576 + lane];   // 592 = 9*64+16
        __builtin_amdgcn_s_waitcnt(0);
        SOFTMAX(X0);
        __builtin_amdgcn_s_waitcnt(0);
    }

    const int NC = T >> 6;            // chunks of 64 (T % 64 == 0 on this path)
    float pw[16];                     // rotating window, static indices only
    #pragma unroll 1
    for (int c = 0; c < NC; ++c) {
        const float* Xb = (c & 1) ? X1 : X0;
        const bool more = (c + 1 < NC);
        const bool first = (c == 0);
        const int tbase = c << 6;

        // (a) issue global loads for chunk c+1 (named regs; hidden by (b))
        float4 f0 = {}, f1 = {}, f2 = {}, f3 = {}, f4 = {},
               f5 = {}, f6 = {}, f7 = {}, f8 = {}, f9 = {};
        if (more) {
            const float4* s2g = src + (size_t)(c + 1) * 592;
            f0 = s2g[lane];       f1 = s2g[64 + lane];  f2 = s2g[128 + lane];
            f3 = s2g[192 + lane]; f4 = s2g[256 + lane]; f5 = s2g[320 + lane];
            f6 = s2g[384 + lane]; f7 = s2g[448 + lane]; f8 = s2g[512 + lane];
            if (lane < 16) f9 = s2g[576 + lane];
        }

        // (b) 64 steps; 16-deep static-window gather lookahead
        #pragma unroll
        for (int j = 0; j < 16; ++j) pw[j] = Xb[j * CC + ext_s];
        #pragma unroll
        for (int r = 0; r < 64; ++r) {
            const float p = pw[r & 15];
            if (r + 16 < 64) pw[r & 15] = Xb[(r + 16) * CC + ext_s];
            if (r == 0) {
                if (first) {
                    z = ((lane <= 1) ? p : 0.0f) * validm;
                    if (ilen_s == 1) capv = __logf(fmaxf(z, 1e-35f)) - LOG37;
                } else {
                    STEP(p, tbase);
                }
            } else {
                STEP(p, tbase + r);
            }
            if ((r & 15) == 15) RESCALE();   // every 16 steps
        }

        // (c) commit staged chunk c+1, softmax rows in place
        if (more) {
            float* Xn = (c & 1) ? X0 : X1;
            float4* dst = (float4*)Xn;
            dst[lane] = f0;       dst[64 + lane] = f1;  dst[128 + lane] = f2;
            dst[192 + lane] = f3; dst[256 + lane] = f4; dst[320 + lane] = f5;
            dst[384 + lane] = f6; dst[448 + lane] = f7; dst[512 + lane] = f8;
            if (lane < 16) dst[576 + lane] = f9;
            __builtin_amdgcn_s_waitcnt(0);
            SOFTMAX(Xn);
            __builtin_amdgcn_s_waitcnt(0);
        }
    }

    // ---- final_ll once ----
    const float e1 = __shfl(capv, end_s);
    const float e2 = __shfl(capv, end_s - 1);
    const float final_v = logaddexp_f(e1, e2);
    if (lane == 0) per_sample[b] = -final_v / (float)tlen_s;
}

// ============ FALLBACK PATH (proven R2 kernels) ============================
__global__ __launch_bounds__(256) void lse_kernel(
    const float* __restrict__ logits, float* __restrict__ denom, int N)
{
    __shared__ float lds[256 * CC];
    const int lane = threadIdx.x & 63;
    const int wib  = threadIdx.x >> 6;
    const int wave = blockIdx.x * 4 + wib;
    const long long row0 = (long long)wave * 64;
    if (row0 >= N) return;
    const int wbase = wib * 64 * CC;
    const float4* src4 = (const float4*)(logits + row0 * CC);
    const long long n4_remaining = ((long long)N * CC - row0 * CC) / 4;
    float4* lds4 = (float4*)(lds + wbase);
    #pragma unroll
    for (int k = 0; k < 10; ++k) {
        const int idx = k * 64 + lane;
        if (idx < 592 && idx < n4_remaining) lds4[idx] = src4[idx];
    }
    __builtin_amdgcn_s_waitcnt(0);
    const long long row = row0 + lane;
    if (row >= N) return;
    const float* x = lds + wbase + lane * CC;
    float m = x[0];
    #pragma unroll
    for (int c = 1; c < CC; ++c) m = fmaxf(m, x[c]);
    float s = 0.0f;
    #pragma unroll
    for (int c = 0; c < CC; ++c) s += __expf(x[c] - m);
    denom[row] = m + __logf(s);
}

__global__ __launch_bounds__(256) void ctc_alpha2_kernel(
    const float* __restrict__ logits, const float* __restrict__ denom,
    const int* __restrict__ targets, const int* __restrict__ input_lengths,
    const int* __restrict__ target_lengths, float* __restrict__ per_sample,
    int B, int T, int L)
{
    const int wave = (int)((blockIdx.x * blockDim.x + threadIdx.x) >> 6);
    const int lane = threadIdx.x & 63;
    if (wave >= B) return;
    const int b = wave;
    const int S = 2 * L + 1;
    const int tlen = target_lengths[b];
    const int ilen = input_lengths[b];
    const int end_idx = 2 * tlen;
    int ext_s = BLANK;
    if (lane < S && (lane & 1)) ext_s = targets[b * L + (lane >> 1)];
    const int ext_sm2 = __shfl_up(ext_s, 2);
    const bool skip_ok = (lane < S) && (lane >= 2) && (ext_s != BLANK) && (ext_s != ext_sm2);
    const bool valid = lane < (2 * tlen + 1);
    const float* lg = logits + (size_t)b * T * CC;
    const float* dn = denom + (size_t)b * T;
    float x_cur = lg[ext_s];
    float d_cur = dn[0];
    float x_nx = (T > 1) ? lg[CC + ext_s] : 0.0f;
    float d_nx = (T > 1) ? dn[1] : 0.0f;
    float final_v = NEG;
    float alpha = (valid && lane <= 1) ? (x_cur - d_cur) : NEG;
    if (ilen == 1) {
        const float e1 = __shfl(alpha, end_idx);
        const float e2 = __shfl(alpha, end_idx - 1);
        final_v = logaddexp_f(e1, e2);
    }
    for (int tt = 1; tt < T; ++tt) {
        x_cur = x_nx; d_cur = d_nx;
        if (tt + 1 < T) {
            x_nx = lg[(size_t)(tt + 1) * CC + ext_s];
            d_nx = dn[tt + 1];
        }
        const float lpe = x_cur - d_cur;
        float a1 = __shfl_up(alpha, 1);
        if (lane == 0) a1 = NEG;
        float a2 = __shfl_up(alpha, 2);
        if (!skip_ok) a2 = NEG;
        const float m = fmaxf(fmaxf(alpha, a1), a2);
        const float s = __expf(alpha - m) + __expf(a1 - m) + __expf(a2 - m);
        const float na = m + __logf(s) + lpe;
        alpha = valid ? na : NEG;
        if (ilen == tt + 1) {
            const float e1 = __shfl(alpha, end_idx);
            const float e2 = __shfl(alpha, end_idx - 1);
            final_v = logaddexp_f(e1, e2);
        }
    }
    if (lane == 0) per_sample[b] = -final_v / (float)tlen;
}

__global__ __launch_bounds__(256) void ctc_alpha_mono_kernel(
    const float* __restrict__ logits, const int* __restrict__ targets,
    const int* __restrict__ input_lengths, const int* __restrict__ target_lengths,
    float* __restrict__ per_sample, int B, int T, int L)
{
    const int wave = (int)((blockIdx.x * blockDim.x + threadIdx.x) >> 6);
    const int lane = threadIdx.x & 63;
    if (wave >= B) return;
    const int b = wave;
    const int S = 2 * L + 1;
    const int tlen = target_lengths[b];
    const int ilen = input_lengths[b];
    const int end_idx = 2 * tlen;
    int ext_s = BLANK;
    if (lane < S && (lane & 1)) ext_s = targets[b * L + (lane >> 1)];
    const int ext_sm2 = __shfl_up(ext_s, 2);
    const bool skip_ok = (lane < S) && (lane >= 2) && (ext_s != BLANK) && (ext_s != ext_sm2);
    const bool valid = lane < (2 * tlen + 1);
    const float* lg = logits + (size_t)b * T * CC;
    float alpha = NEG, final_v = NEG;
    for (int t = 0; t < T; ++t) {
        float x = (lane < CC) ? lg[t * CC + lane] : -3.0e38f;
        float mx = x;
        #pragma unroll
        for (int o = 32; o > 0; o >>= 1) mx = fmaxf(mx, __shfl_xor(mx, o));
        float e = (lane < CC) ? __expf(x - mx) : 0.0f;
        float se = e;
        #pragma unroll
        for (int o = 32; o > 0; o >>= 1) se += __shfl_xor(se, o);
        const float lp = x - mx - __logf(se);
        const float lpe = __shfl(lp, ext_s);
        float newa;
        if (t == 0) {
            newa = (lane <= 1) ? lpe : NEG;
        } else {
            float a1 = __shfl_up(alpha, 1);
            if (lane == 0) a1 = NEG;
            float a2 = __shfl_up(alpha, 2);
            if (!skip_ok) a2 = NEG;
            newa = logaddexp_f(logaddexp_f(alpha, a1), a2) + lpe;
        }
        if (!valid) newa = NEG;
        alpha = newa;
        if (ilen == t + 1) {
            const float e1 = __shfl(alpha, end_idx);
            const float e2 = __shfl(alpha, end_idx - 1);
            final_v = logaddexp_f(e1, e2);
        }
    }
    if (lane == 0) per_sample[b] = -final_v / (float)tlen;
}

// ---------------- Deterministic mean over B samples ------------------------
__global__ __launch_bounds__(256) void reduce_mean_kernel(
    const float* __restrict__ ps, float* __restrict__ out, int B)
{
    float s = 0.0f;
    for (int i = threadIdx.x; i < B; i += 256) s += ps[i];
    #pragma unroll
    for (int o = 32; o > 0; o >>= 1) s += __shfl_xor(s, o);
    __shared__ float sm[4];
    const int w = threadIdx.x >> 6, l = threadIdx.x & 63;
    if (l == 0) sm[w] = s;
    __syncthreads();
    if (threadIdx.x == 0) {
        out[0] = (sm[0] + sm[1] + sm[2] + sm[3]) / (float)B;
    }
}

extern "C" void kernel_launch(void* const* d_in, const int* in_sizes, int n_in,
                              void* d_out, int out_size, void* d_ws, size_t ws_size,
                              hipStream_t stream) {
    const float* logits         = (const float*)d_in[0];
    const int*   targets        = (const int*)d_in[1];
    const int*   input_lengths  = (const int*)d_in[2];
    const int*   target_lengths = (const int*)d_in[3];

    const int B = in_sizes[2];
    const int L = in_sizes[1] / B;
    const int T = in_sizes[0] / (B * CC);
    const long long N = (long long)B * T;

    float* per_sample = (float*)d_ws;
    float* scratch    = per_sample + B;
    float* out        = (float*)d_out;

    const size_t ws_mid = ((size_t)B + (size_t)N) * sizeof(float);
    const int nblocks_alpha = (B * 64 + 255) / 256;
    const long long nwaves = (N + 63) / 64;

    if ((T % 64 == 0) && T >= 64 && L <= 31 && ws_size >= (size_t)B * sizeof(float)) {
        ctc_fused_dpp16_kernel<<<(B + 1) / 2, 128, 0, stream>>>(
            logits, targets, input_lengths, target_lengths, per_sample, B, T, L);
    } else if (ws_size >= ws_mid && T >= 2) {
        lse_kernel<<<(int)((nwaves + 3) / 4), 256, 0, stream>>>(logits, scratch, (int)N);
        ctc_alpha2_kernel<<<nblocks_alpha, 256, 0, stream>>>(
            logits, scratch, targets, input_lengths, target_lengths, per_sample, B, T, L);
    } else {
        ctc_alpha_mono_kernel<<<nblocks_alpha, 256, 0, stream>>>(
            logits, targets, input_lengths, target_lengths, per_sample, B, T, L);
    }
    reduce_mean_kernel<<<1, 256, 0, stream>>>(per_sample, out, B);
}

// Round 13
// 135.293 us; speedup vs baseline: 1.0545x; 1.0196x over previous
//
#include <hip/hip_runtime.h>

#define BLANK 36
#define NEG -1e30f
#define CC 37
#define LOG37 3.6109179126442243f

__device__ __forceinline__ float logaddexp_f(float a, float b) {
    float m = fmaxf(a, b);
    float d = fabsf(a - b);
    return m + __logf(1.0f + __expf(-d));
}

// DPP helpers (VALU pipe): 0x110|n = row_shr:n, 0x142 = row_bcast15,
// 0x143 = row_bcast31. bound_ctrl=true -> OOB lanes read 0.
#define DPP0(src, ctrl) __builtin_amdgcn_update_dpp(0, (src), (ctrl), 0xf, 0xf, true)
#define DPPM(old, src, ctrl) __builtin_amdgcn_update_dpp((old), (src), (ctrl), 0xf, 0xf, false)

// ============ FAST PATH: alpha/beta split, one block (2 waves) per sample ==
// R12 post-mortem: VALUBusy 66% at 2 waves/SIMD -> throughput-near; levers
// left are occupancy and serial length. This kernel: wave0 runs alpha
// forward t=0..T/2-1; wave1 runs beta backward t=T-1..T/2 (state axis
// REVERSED in lanes so the verified row_shr DPP code is reused); combine via
// CTC identity P = sum_s alpha_tm[s]*beta_tm[s] at tm=T/2-1. 128 serial
// steps/wave (half) and 19.2 KB LDS/block -> 8 blocks/CU = 4 waves/SIMD
// (double). General ilen: <=T/2 -> alpha capture path; >T/2 -> beta
// re-inits at t=ilen-1 and midpoint product is used.
__global__ __launch_bounds__(128, 4) void ctc_fused_ab_kernel(
    const float* __restrict__ logits,        // [B, T, C]
    const int*   __restrict__ targets,       // [B * L]
    const int*   __restrict__ input_lengths, // [B]
    const int*   __restrict__ target_lengths,// [B]
    float*       __restrict__ per_sample,    // [B]
    int B, int T, int L)
{
    __shared__ float lds[2 * 2368 + 66];
    const int lane = threadIdx.x & 63;
    const int wib  = threadIdx.x >> 6;       // 0 = alpha, 1 = beta
    const int b    = blockIdx.x;

    float* Xw   = lds + wib * 2368;          // this wave's chunk buffer
    float* exch = lds + 4736;                // combine exchange (65 floats)

    const int S = 2 * L + 1;
    const int tlen_s = __builtin_amdgcn_readfirstlane(target_lengths[b]);
    const int ilen_s = __builtin_amdgcn_readfirstlane(input_lengths[b]);
    const int end_s  = 2 * tlen_s;
    const int halfT  = T >> 1;
    const int NC     = T >> 6;               // 64-row chunks (NC even)
    const int NCh    = NC >> 1;              // chunks per wave

    // per-wave state<->lane mapping: alpha natural, beta reversed
    const int st = (wib == 0) ? lane : (63 - lane);
    int ext_w = BLANK;
    if (st < S && (st & 1)) ext_w = targets[b * L + (st >> 1)];
    const int exo = __shfl_up(ext_w, 2);     // alpha: ext[st-2]; beta: ext[st+2]
    float kf;
    if (wib == 0)
        kf = ((st >= 2) && (st < S) && (ext_w != BLANK) && (ext_w != exo)) ? 1.0f : 0.0f;
    else
        kf = ((st + 2 < S) && (exo != BLANK) && (exo != ext_w)) ? 1.0f : 0.0f;

    // row-boundary lanes for the DPP shift patches (verified R10-R12)
    const bool c16 = ((lane & 31) == 16);
    const bool c17 = ((lane & 31) == 17);
    const bool c32 = (lane == 32);
    const bool c33 = (lane == 33);

    const float4* src = (const float4*)(logits + (size_t)b * T * CC);

    // shifted neighbors (x[l-1], x[l-2]) with row-boundary patches
    auto SHIFTS = [&](float x, float& a1, float& a2) {
        const int xi  = __float_as_int(x);
        const int s1  = DPP0(xi, 0x111);
        const int s2  = DPP0(xi, 0x112);
        const int b15 = DPP0(xi, 0x142);
        const int b31 = DPP0(xi, 0x143);
        const int y15 = DPP0(s1, 0x142);
        const int y31 = DPP0(s1, 0x143);
        a1 = __int_as_float(c16 ? b15 : (c32 ? b31 : s1));
        a2 = __int_as_float(c16 ? y15 : (c17 ? b15 : (c32 ? y31 : (c33 ? b31 : s2))));
    };

    auto RESCALE = [&](float& x, float& racc) {  // DPP reduce + readlane
        float m = x;
        m = fmaxf(m, __int_as_float(DPPM(__float_as_int(m), __float_as_int(m), 0x111)));
        m = fmaxf(m, __int_as_float(DPPM(__float_as_int(m), __float_as_int(m), 0x112)));
        m = fmaxf(m, __int_as_float(DPPM(__float_as_int(m), __float_as_int(m), 0x114)));
        m = fmaxf(m, __int_as_float(DPPM(__float_as_int(m), __float_as_int(m), 0x118)));
        m = fmaxf(m, __int_as_float(DPPM(__float_as_int(m), __float_as_int(m), 0x142)));
        m = fmaxf(m, __int_as_float(DPPM(__float_as_int(m), __float_as_int(m), 0x143)));
        float gm = __int_as_float(__builtin_amdgcn_readlane(__float_as_int(m), 63));
        gm = fmaxf(gm, 1e-30f);
        x *= (1.0f / gm);
        racc += __logf(gm);
    };

    auto SOFTMAX = [&](float* Xn) {          // in-place row softmax scaled by 37
        float xr[CC];
        const float* row = Xn + lane * CC;
        #pragma unroll
        for (int c2 = 0; c2 < CC; ++c2) xr[c2] = row[c2];
        float m = xr[0];
        #pragma unroll
        for (int c2 = 1; c2 < CC; ++c2) m = fmaxf(m, xr[c2]);
        float ss = 0.0f;
        #pragma unroll
        for (int c2 = 0; c2 < CC; ++c2) { xr[c2] = __expf(xr[c2] - m); ss += xr[c2]; }
        const float inv = 37.0f / ss;
        float* wrow = Xn + lane * CC;
        #pragma unroll
        for (int c2 = 0; c2 < CC; ++c2) wrow[c2] = xr[c2] * inv;
    };

    auto STAGE = [&](const float4* s2g) {    // global -> this wave's buffer
        float4* dst = (float4*)Xw;
        #pragma unroll
        for (int k = 0; k < 9; ++k) dst[k * 64 + lane] = s2g[k * 64 + lane];
        if (lane < 16) dst[576 + lane] = s2g[576 + lane];
        __builtin_amdgcn_s_waitcnt(0);
    };

    float z = 0.0f, racc = 0.0f, capv = NEG; // z: alpha (w0) / beta (w1)
    float pw[16];

    if (wib == 0) {
        // =================== ALPHA: t = 0 .. halfT-1 =======================
        STAGE(src);
        SOFTMAX(Xw);
        __builtin_amdgcn_s_waitcnt(0);
        #pragma unroll 1
        for (int c = 0; c < NCh; ++c) {
            const bool more = (c + 1 < NCh);
            float4 f0 = {}, f1 = {}, f2 = {}, f3 = {}, f4 = {},
                   f5 = {}, f6 = {}, f7 = {}, f8 = {}, f9 = {};
            if (more) {
                const float4* s2g = src + (size_t)(c + 1) * 592;
                f0 = s2g[lane];       f1 = s2g[64 + lane];  f2 = s2g[128 + lane];
                f3 = s2g[192 + lane]; f4 = s2g[256 + lane]; f5 = s2g[320 + lane];
                f6 = s2g[384 + lane]; f7 = s2g[448 + lane]; f8 = s2g[512 + lane];
                if (lane < 16) f9 = s2g[576 + lane];
            }
            const int tbase = c << 6;
            #pragma unroll
            for (int j = 0; j < 16; ++j) pw[j] = Xw[j * CC + ext_w];
            #pragma unroll
            for (int r = 0; r < 64; ++r) {
                const float p = pw[r & 15];
                if (r + 16 < 64) pw[r & 15] = Xw[(r + 16) * CC + ext_w];
                if (c == 0 && r == 0) {
                    z = (lane <= 1) ? p : 0.0f;
                    if (ilen_s == 1) capv = __logf(fmaxf(z, 1e-35f)) - LOG37;
                } else {
                    float a1, a2;
                    SHIFTS(z, a1, a2);
                    z = fmaf(kf, a2, z + a1) * p;
                    const int tt = tbase + r;
                    if (ilen_s == tt + 1)
                        capv = __logf(fmaxf(z, 1e-35f)) + racc - (float)(tt + 1) * LOG37;
                }
                if ((r & 15) == 15) RESCALE(z, racc);
            }
            if (more) {
                float4* dst = (float4*)Xw;
                dst[lane] = f0;       dst[64 + lane] = f1;  dst[128 + lane] = f2;
                dst[192 + lane] = f3; dst[256 + lane] = f4; dst[320 + lane] = f5;
                dst[384 + lane] = f6; dst[448 + lane] = f7; dst[512 + lane] = f8;
                if (lane < 16) dst[576 + lane] = f9;
                __builtin_amdgcn_s_waitcnt(0);
                SOFTMAX(Xw);
                __builtin_amdgcn_s_waitcnt(0);
            }
        }
    } else {
        // =================== BETA: t = T-1 .. halfT (reversed states) ======
        // v[l] = beta[63-l] (scaled). Step: u = v*p_tt; beta_{tt-1}[s] =
        // u[s] + u[s+1] + kf*u[s+2] -> lanes l, l-1, l-2 -> same SHIFTS code.
        STAGE(src + (size_t)(NC - 1) * 592);
        SOFTMAX(Xw);
        __builtin_amdgcn_s_waitcnt(0);
        const int il1 = ilen_s - 1;
        #pragma unroll 1
        for (int i = 0; i < NCh; ++i) {
            const bool more = (i + 1 < NCh);
            float4 f0 = {}, f1 = {}, f2 = {}, f3 = {}, f4 = {},
                   f5 = {}, f6 = {}, f7 = {}, f8 = {}, f9 = {};
            if (more) {
                const float4* s2g = src + (size_t)(NC - 2 - i) * 592;
                f0 = s2g[lane];       f1 = s2g[64 + lane];  f2 = s2g[128 + lane];
                f3 = s2g[192 + lane]; f4 = s2g[256 + lane]; f5 = s2g[320 + lane];
                f6 = s2g[384 + lane]; f7 = s2g[448 + lane]; f8 = s2g[512 + lane];
                if (lane < 16) f9 = s2g[576 + lane];
            }
            const int cbase = (NC - 1 - i) << 6;
            #pragma unroll
            for (int j = 0; j < 16; ++j) pw[j] = Xw[(63 - j) * CC + ext_w];
            #pragma unroll
            for (int r = 0; r < 64; ++r) {
                const int tt = cbase + 63 - r;
                if (tt == il1) {                 // wave-uniform re-init
                    z = (lane == 63 - end_s || lane == 64 - end_s) ? 1.0f : 0.0f;
                    racc = 0.0f;
                }
                const float p = pw[r & 15];
                if (r + 16 < 64) pw[r & 15] = Xw[(63 - (r + 16)) * CC + ext_w];
                const float u = z * p;
                float a1, a2;
                SHIFTS(u, a1, a2);
                z = fmaf(kf, a2, u + a1);
                if ((r & 15) == 15) RESCALE(z, racc);
            }
            if (more) {
                float4* dst = (float4*)Xw;
                dst[lane] = f0;       dst[64 + lane] = f1;  dst[128 + lane] = f2;
                dst[192 + lane] = f3; dst[256 + lane] = f4; dst[320 + lane] = f5;
                dst[384 + lane] = f6; dst[448 + lane] = f7; dst[512 + lane] = f8;
                if (lane < 16) dst[576 + lane] = f9;
                __builtin_amdgcn_s_waitcnt(0);
                SOFTMAX(Xw);
                __builtin_amdgcn_s_waitcnt(0);
            }
        }
    }

    // =================== combine ==========================================
    __syncthreads();
    if (wib == 1) {
        exch[63 - lane] = z;                 // exch[state] = beta_tm[state]
        if (lane == 0) exch[64] = racc;
    }
    __syncthreads();
    if (wib == 0) {
        const float bs = exch[lane];         // beta at my state (0 if invalid)
        const float rb = exch[64];
        float prod = z * bs;                 // garbage alpha lanes x 0 = 0
        #pragma unroll
        for (int o = 32; o > 0; o >>= 1) prod += __shfl_xor(prod, o);
        float final_v;
        if (ilen_s <= halfT) {               // alpha capture path
            const float e1 = __shfl(capv, end_s);
            const float e2 = __shfl(capv, end_s - 1);
            final_v = logaddexp_f(e1, e2);
        } else {                             // midpoint product path
            final_v = __logf(fmaxf(prod, 1e-37f)) + racc + rb - (float)ilen_s * LOG37;
        }
        if (lane == 0) per_sample[b] = -final_v / (float)tlen_s;
    }
}

// ============ FALLBACK PATH (proven R2 kernels) ============================
__global__ __launch_bounds__(256) void lse_kernel(
    const float* __restrict__ logits, float* __restrict__ denom, int N)
{
    __shared__ float lds[256 * CC];
    const int lane = threadIdx.x & 63;
    const int wib  = threadIdx.x >> 6;
    const int wave = blockIdx.x * 4 + wib;
    const long long row0 = (long long)wave * 64;
    if (row0 >= N) return;
    const int wbase = wib * 64 * CC;
    const float4* src4 = (const float4*)(logits + row0 * CC);
    const long long n4_remaining = ((long long)N * CC - row0 * CC) / 4;
    float4* lds4 = (float4*)(lds + wbase);
    #pragma unroll
    for (int k = 0; k < 10; ++k) {
        const int idx = k * 64 + lane;
        if (idx < 592 && idx < n4_remaining) lds4[idx] = src4[idx];
    }
    __builtin_amdgcn_s_waitcnt(0);
    const long long row = row0 + lane;
    if (row >= N) return;
    const float* x = lds + wbase + lane * CC;
    float m = x[0];
    #pragma unroll
    for (int c = 1; c < CC; ++c) m = fmaxf(m, x[c]);
    float s = 0.0f;
    #pragma unroll
    for (int c = 0; c < CC; ++c) s += __expf(x[c] - m);
    denom[row] = m + __logf(s);
}

__global__ __launch_bounds__(256) void ctc_alpha2_kernel(
    const float* __restrict__ logits, const float* __restrict__ denom,
    const int* __restrict__ targets, const int* __restrict__ input_lengths,
    const int* __restrict__ target_lengths, float* __restrict__ per_sample,
    int B, int T, int L)
{
    const int wave = (int)((blockIdx.x * blockDim.x + threadIdx.x) >> 6);
    const int lane = threadIdx.x & 63;
    if (wave >= B) return;
    const int b = wave;
    const int S = 2 * L + 1;
    const int tlen = target_lengths[b];
    const int ilen = input_lengths[b];
    const int end_idx = 2 * tlen;
    int ext_s = BLANK;
    if (lane < S && (lane & 1)) ext_s = targets[b * L + (lane >> 1)];
    const int ext_sm2 = __shfl_up(ext_s, 2);
    const bool skip_ok = (lane < S) && (lane >= 2) && (ext_s != BLANK) && (ext_s != ext_sm2);
    const bool valid = lane < (2 * tlen + 1);
    const float* lg = logits + (size_t)b * T * CC;
    const float* dn = denom + (size_t)b * T;
    float x_cur = lg[ext_s];
    float d_cur = dn[0];
    float x_nx = (T > 1) ? lg[CC + ext_s] : 0.0f;
    float d_nx = (T > 1) ? dn[1] : 0.0f;
    float final_v = NEG;
    float alpha = (valid && lane <= 1) ? (x_cur - d_cur) : NEG;
    if (ilen == 1) {
        const float e1 = __shfl(alpha, end_idx);
        const float e2 = __shfl(alpha, end_idx - 1);
        final_v = logaddexp_f(e1, e2);
    }
    for (int tt = 1; tt < T; ++tt) {
        x_cur = x_nx; d_cur = d_nx;
        if (tt + 1 < T) {
            x_nx = lg[(size_t)(tt + 1) * CC + ext_s];
            d_nx = dn[tt + 1];
        }
        const float lpe = x_cur - d_cur;
        float a1 = __shfl_up(alpha, 1);
        if (lane == 0) a1 = NEG;
        float a2 = __shfl_up(alpha, 2);
        if (!skip_ok) a2 = NEG;
        const float m = fmaxf(fmaxf(alpha, a1), a2);
        const float s = __expf(alpha - m) + __expf(a1 - m) + __expf(a2 - m);
        const float na = m + __logf(s) + lpe;
        alpha = valid ? na : NEG;
        if (ilen == tt + 1) {
            const float e1 = __shfl(alpha, end_idx);
            const float e2 = __shfl(alpha, end_idx - 1);
            final_v = logaddexp_f(e1, e2);
        }
    }
    if (lane == 0) per_sample[b] = -final_v / (float)tlen;
}

__global__ __launch_bounds__(256) void ctc_alpha_mono_kernel(
    const float* __restrict__ logits, const int* __restrict__ targets,
    const int* __restrict__ input_lengths, const int* __restrict__ target_lengths,
    float* __restrict__ per_sample, int B, int T, int L)
{
    const int wave = (int)((blockIdx.x * blockDim.x + threadIdx.x) >> 6);
    const int lane = threadIdx.x & 63;
    if (wave >= B) return;
    const int b = wave;
    const int S = 2 * L + 1;
    const int tlen = target_lengths[b];
    const int ilen = input_lengths[b];
    const int end_idx = 2 * tlen;
    int ext_s = BLANK;
    if (lane < S && (lane & 1)) ext_s = targets[b * L + (lane >> 1)];
    const int ext_sm2 = __shfl_up(ext_s, 2);
    const bool skip_ok = (lane < S) && (lane >= 2) && (ext_s != BLANK) && (ext_s != ext_sm2);
    const bool valid = lane < (2 * tlen + 1);
    const float* lg = logits + (size_t)b * T * CC;
    float alpha = NEG, final_v = NEG;
    for (int t = 0; t < T; ++t) {
        float x = (lane < CC) ? lg[t * CC + lane] : -3.0e38f;
        float mx = x;
        #pragma unroll
        for (int o = 32; o > 0; o >>= 1) mx = fmaxf(mx, __shfl_xor(mx, o));
        float e = (lane < CC) ? __expf(x - mx) : 0.0f;
        float se = e;
        #pragma unroll
        for (int o = 32; o > 0; o >>= 1) se += __shfl_xor(se, o);
        const float lp = x - mx - __logf(se);
        const float lpe = __shfl(lp, ext_s);
        float newa;
        if (t == 0) {
            newa = (lane <= 1) ? lpe : NEG;
        } else {
            float a1 = __shfl_up(alpha, 1);
            if (lane == 0) a1 = NEG;
            float a2 = __shfl_up(alpha, 2);
            if (!skip_ok) a2 = NEG;
            newa = logaddexp_f(logaddexp_f(alpha, a1), a2) + lpe;
        }
        if (!valid) newa = NEG;
        alpha = newa;
        if (ilen == t + 1) {
            const float e1 = __shfl(alpha, end_idx);
            const float e2 = __shfl(alpha, end_idx - 1);
            final_v = logaddexp_f(e1, e2);
        }
    }
    if (lane == 0) per_sample[b] = -final_v / (float)tlen;
}

// ---------------- Deterministic mean over B samples ------------------------
__global__ __launch_bounds__(256) void reduce_mean_kernel(
    const float* __restrict__ ps, float* __restrict__ out, int B)
{
    float s = 0.0f;
    for (int i = threadIdx.x; i < B; i += 256) s += ps[i];
    #pragma unroll
    for (int o = 32; o > 0; o >>= 1) s += __shfl_xor(s, o);
    __shared__ float sm[4];
    const int w = threadIdx.x >> 6, l = threadIdx.x & 63;
    if (l == 0) sm[w] = s;
    __syncthreads();
    if (threadIdx.x == 0) {
        out[0] = (sm[0] + sm[1] + sm[2] + sm[3]) / (float)B;
    }
}

extern "C" void kernel_launch(void* const* d_in, const int* in_sizes, int n_in,
                              void* d_out, int out_size, void* d_ws, size_t ws_size,
                              hipStream_t stream) {
    const float* logits         = (const float*)d_in[0];
    const int*   targets        = (const int*)d_in[1];
    const int*   input_lengths  = (const int*)d_in[2];
    const int*   target_lengths = (const int*)d_in[3];

    const int B = in_sizes[2];
    const int L = in_sizes[1] / B;
    const int T = in_sizes[0] / (B * CC);
    const long long N = (long long)B * T;

    float* per_sample = (float*)d_ws;
    float* scratch    = per_sample + B;
    float* out        = (float*)d_out;

    const size_t ws_mid = ((size_t)B + (size_t)N) * sizeof(float);
    const int nblocks_alpha = (B * 64 + 255) / 256;
    const long long nwaves = (N + 63) / 64;

    if ((T % 128 == 0) && T >= 128 && L <= 31 && ws_size >= (size_t)B * sizeof(float)) {
        ctc_fused_ab_kernel<<<B, 128, 0, stream>>>(
            logits, targets, input_lengths, target_lengths, per_sample, B, T, L);
    } else if (ws_size >= ws_mid && T >= 2) {
        lse_kernel<<<(int)((nwaves + 3) / 4), 256, 0, stream>>>(logits, scratch, (int)N);
        ctc_alpha2_kernel<<<nblocks_alpha, 256, 0, stream>>>(
            logits, scratch, targets, input_lengths, target_lengths, per_sample, B, T, L);
    } else {
        ctc_alpha_mono_kernel<<<nblocks_alpha, 256, 0, stream>>>(
            logits, targets, input_lengths, target_lengths, per_sample, B, T, L);
    }
    reduce_mean_kernel<<<1, 256, 0, stream>>>(per_sample, out, B);
}